// Round 8
// baseline (30.905 us; speedup 1.0000x reference)
//
#include <hip/hip_runtime.h>
#include <hip/hip_bf16.h>

// SlotModel: B=2048, L=512, H=64, VOCAB=64, k=6 slots.
// Single plain dispatch: every block redundantly computes the 64-token
// h/norm tables, then consumes its 8 batch rows. Round-7 lesson: weight
// loads must NOT be uniform-address global loads (VMEM issue/latency bound,
// or SMEM+DS lgkmcnt(0) serialization). This version stages ALL weights to
// LDS (f32-normalized), so inner loops are only: conflict-free ds_read_b32
// (lane=token activation) + same-address-broadcast ds_read_b128 (weights)
// + v_fmac. LDS is in-order -> counted waits -> fully pipelined.

#define LSEQ 512
#define BODY 509       // L-3 positions eligible for slots
#define KSLOTS 6
#define INF_KEY 0x7FFFFFFF

struct Smem {
  float e[64 * 64];    // [k][v] = embed^T; after S3 holds (e+ff)^T in place
  float h1[128 * 64];  // [c][v] relu(fc1)
  float w[8192];       // staged weights: W1(64x128) -> W2(128x64) -> Wq|Wo
  float ht[64 * 65];   // [v][t] final h, pad 65 -> bank=(v+t)%32
  float nrm[64];
  float P[448];        // b1[128] b2[64] gamma[64] beta[64] bq[64] bo[64]
};

__device__ __forceinline__ float wsum(float x) {
#pragma unroll
  for (int off = 32; off >= 1; off >>= 1) x += __shfl_xor(x, off, 64);
  return x;
}

// Dtype probe (verified rounds 2-7): first 256 ushorts of embed.
__device__ __forceinline__ bool probe_bf16(const void* embed) {
  const ushort* e = (const ushort*)embed;
  const int lane = threadIdx.x & 63;
  bool bad = false;
#pragma unroll
  for (int i = 0; i < 4; ++i) {
    const int exp = (e[lane * 4 + i] >> 7) & 0xFF;
    if (exp >= 127) bad = true;
  }
  return !__any(bad);
}

template <bool BF>
__device__ __forceinline__ float ldel(const void* p, int i) {
  if (BF) return __bfloat162float(((const __hip_bfloat16*)p)[i]);
  return ((const float*)p)[i];
}

// Coalesced stage of nelem (multiple of 4) elems from global W into LDS f32.
// Threads tid0..tid0+nthr-1 participate; 4 elems per thread per step.
template <bool BF>
__device__ __forceinline__ void stage_w(const void* W, float* dst, int nelem,
                                        int t, int nthr) {
  for (int base = t * 4; base < nelem; base += nthr * 4) {
    if (BF) {
      const uint2 u = *(const uint2*)((const ushort*)W + base);
      float4 v;
      v.x = __uint_as_float(u.x << 16);
      v.y = __uint_as_float(u.x & 0xFFFF0000u);
      v.z = __uint_as_float(u.y << 16);
      v.w = __uint_as_float(u.y & 0xFFFF0000u);
      *(float4*)&dst[base] = v;
    } else {
      *(float4*)&dst[base] = *(const float4*)((const float*)W + base);
    }
  }
}

template <bool BF>
__device__ void fused_body(const int* __restrict__ seq, const void* embed,
                           const void* W1, const void* b1, const void* W2,
                           const void* b2, const void* gamma, const void* beta,
                           const void* Wq, const void* bq, const void* Wo,
                           const void* bo, void* out, Smem& sm) {
  const int tid = threadIdx.x;
  const int wave = tid >> 6, lane = tid & 63;

  // --- prefetch this wave's 2 seq rows (HBM latency hides under producer) ---
  const int row0 = blockIdx.x * 8 + wave * 2;
  const int4 a0 = *(const int4*)(seq + row0 * LSEQ + 8 * lane);
  const int4 a1 = *(const int4*)(seq + row0 * LSEQ + 8 * lane + 4);
  const int4 c0 = *(const int4*)(seq + (row0 + 1) * LSEQ + 8 * lane);
  const int4 c1 = *(const int4*)(seq + (row0 + 1) * LSEQ + 8 * lane + 4);

  // ---- S0: stage W1, embed^T, params ----
  stage_w<BF>(W1, sm.w, 8192, tid, 256);
  {
    const int v = tid >> 2;
    const int k0 = (tid & 3) << 4;
#pragma unroll
    for (int j = 0; j < 16; ++j)
      sm.e[(k0 + j) * 64 + v] = ldel<BF>(embed, v * 64 + k0 + j);
  }
#pragma unroll
  for (int i = tid; i < 448; i += 256) {
    float x;
    if (i < 128)      x = ldel<BF>(b1, i);
    else if (i < 192) x = ldel<BF>(b2, i - 128);
    else if (i < 256) x = ldel<BF>(gamma, i - 192);
    else if (i < 320) x = ldel<BF>(beta, i - 256);
    else if (i < 384) x = ldel<BF>(bq, i - 320);
    else              x = ldel<BF>(bo, i - 384);
    sm.P[i] = x;
  }
  __syncthreads();

  // ---- S2: layer 1. lane=token; wave owns cols 32w..32w+31 ----
  {
    const int cb = __builtin_amdgcn_readfirstlane(32 * wave);
    float acc[32];
#pragma unroll
    for (int i = 0; i < 8; ++i) {
      const float4 b = *(const float4*)&sm.P[cb + 4 * i];
      acc[4 * i] = b.x; acc[4 * i + 1] = b.y;
      acc[4 * i + 2] = b.z; acc[4 * i + 3] = b.w;
    }
#pragma unroll 4
    for (int k = 0; k < 64; ++k) {
      const float ek = sm.e[k * 64 + lane];               // conflict-free b32
      const float4* wr = (const float4*)&sm.w[k * 128 + cb];  // broadcast b128
#pragma unroll
      for (int i = 0; i < 8; ++i) {
        const float4 w = wr[i];
        acc[4 * i]     += ek * w.x;
        acc[4 * i + 1] += ek * w.y;
        acc[4 * i + 2] += ek * w.z;
        acc[4 * i + 3] += ek * w.w;
      }
    }
#pragma unroll
    for (int i = 0; i < 32; ++i)
      sm.h1[(cb + i) * 64 + lane] = fmaxf(acc[i], 0.f);
  }
  __syncthreads();

  // ---- stage W2 over the W region ----
  stage_w<BF>(W2, sm.w, 8192, tid, 256);
  __syncthreads();

  // ---- S3: layer 2, accumulate in place into e (residual) ----
  {
    const int cb = __builtin_amdgcn_readfirstlane(16 * wave);
    float acc[16];
#pragma unroll
    for (int i = 0; i < 4; ++i) {
      const float4 b = *(const float4*)&sm.P[128 + cb + 4 * i];
      acc[4 * i] = b.x; acc[4 * i + 1] = b.y;
      acc[4 * i + 2] = b.z; acc[4 * i + 3] = b.w;
    }
#pragma unroll 4
    for (int j = 0; j < 128; ++j) {
      const float hj = sm.h1[j * 64 + lane];              // conflict-free b32
      const float4* wr = (const float4*)&sm.w[j * 64 + cb];   // broadcast b128
#pragma unroll
      for (int i = 0; i < 4; ++i) {
        const float4 w = wr[i];
        acc[4 * i]     += hj * w.x;
        acc[4 * i + 1] += hj * w.y;
        acc[4 * i + 2] += hj * w.z;
        acc[4 * i + 3] += hj * w.w;
      }
    }
#pragma unroll
    for (int i = 0; i < 16; ++i)
      sm.e[(cb + i) * 64 + lane] += acc[i];               // x = e + ff
  }
  __syncthreads();

  // ---- S4: wave0 does in-lane LayerNorm; waves 1-3 stage Wq|Wo ----
  if (wave == 0) {
    float x[64];
    float s = 0.f;
#pragma unroll
    for (int t = 0; t < 64; ++t) {
      x[t] = sm.e[t * 64 + lane];
      s += x[t];
    }
    const float mu = s * (1.f / 64.f);
    float v2 = 0.f;
#pragma unroll
    for (int t = 0; t < 64; ++t) {
      const float d = x[t] - mu;
      v2 += d * d;
    }
    const float rstd = 1.f / sqrtf(v2 * (1.f / 64.f) + 1e-5f);
    float n2 = 0.f;
#pragma unroll
    for (int t = 0; t < 64; ++t) {
      const float h = (x[t] - mu) * rstd * sm.P[192 + t] + sm.P[256 + t];
      sm.ht[lane * 65 + t] = h;   // bank=(lane+t)%32: conflict-free
      n2 += h * h;
    }
    sm.nrm[lane] = sqrtf(n2);
  } else {
    const int t2 = tid - 64;  // 192 threads stage Wq (0..4095) | Wo (4096..8191)
    for (int base = t2 * 4; base < 8192; base += 192 * 4) {
      float4 v;
      if (base < 4096) {
        if (BF) {
          const uint2 u = *(const uint2*)((const ushort*)Wq + base);
          v.x = __uint_as_float(u.x << 16);
          v.y = __uint_as_float(u.x & 0xFFFF0000u);
          v.z = __uint_as_float(u.y << 16);
          v.w = __uint_as_float(u.y & 0xFFFF0000u);
        } else {
          v = *(const float4*)((const float*)Wq + base);
        }
      } else {
        const int o = base - 4096;
        if (BF) {
          const uint2 u = *(const uint2*)((const ushort*)Wo + o);
          v.x = __uint_as_float(u.x << 16);
          v.y = __uint_as_float(u.x & 0xFFFF0000u);
          v.z = __uint_as_float(u.y << 16);
          v.w = __uint_as_float(u.y & 0xFFFF0000u);
        } else {
          v = *(const float4*)((const float*)Wo + o);
        }
      }
      *(float4*)&sm.w[base] = v;
    }
  }
  __syncthreads();

  // ---- S5: consumer (logic verified rounds 4-7), 2 rows per wave ----
  const float* s_wq = sm.w;          // [i][t], i=0..63
  const float* s_wo = sm.w + 4096;   // [i][t]

  const float nv = sm.nrm[lane];
  int rk = 0;
#pragma unroll
  for (int u = 0; u < 64; ++u) rk += (__shfl(nv, u, 64) > nv) ? 1 : 0;

#pragma unroll
  for (int r0 = 0; r0 < 2; ++r0) {
    const int b = row0 + r0;
    const int vals[8] = {r0 ? c0.x : a0.x, r0 ? c0.y : a0.y,
                         r0 ? c0.z : a0.z, r0 ? c0.w : a0.w,
                         r0 ? c1.x : a1.x, r0 ? c1.y : a1.y,
                         r0 ? c1.z : a1.z, r0 ? c1.w : a1.w};
    int keys[8];
#pragma unroll
    for (int i = 0; i < 8; ++i) {
      const int p = 8 * lane + i;
      const int r = __shfl(rk, vals[i], 64);
      keys[i] = (p < BODY) ? ((r << 15) | (p << 6) | vals[i]) : INF_KEY;
    }
    const int v_last = __shfl(vals[7], 63, 64);  // srow[511]

    int winner[KSLOTS];
#pragma unroll
    for (int s = 0; s < KSLOTS; ++s) {
      int lmin = keys[0];
#pragma unroll
      for (int i = 1; i < 8; ++i) lmin = min(lmin, keys[i]);
      int gmin = lmin;
#pragma unroll
      for (int off = 32; off >= 1; off >>= 1)
        gmin = min(gmin, __shfl_xor(gmin, off, 64));
      winner[s] = gmin;
      if (lmin == gmin) {  // keys unique (pos field) -> exactly one match
#pragma unroll
        for (int i = 0; i < 8; ++i)
          if (keys[i] == gmin) keys[i] = INF_KEY;
      }
    }

    // q = h[v_last]@Wq + bq  (Wq from LDS, conflict-free b32)
    const float hq = sm.ht[v_last * 65 + lane];
    float qv = sm.P[320 + lane];
#pragma unroll 8
    for (int i = 0; i < 64; ++i)
      qv += __shfl(hq, i, 64) * s_wq[i * 64 + lane];
    qv *= 0.125f;  // fold 1/sqrt(64) into q

    float hw[KSLOTS], sc[KSLOTS];
#pragma unroll
    for (int s = 0; s < KSLOTS; ++s) {
      hw[s] = sm.ht[(winner[s] & 63) * 65 + lane];
      sc[s] = wsum(qv * hw[s]);
    }
    float m = sc[0];
#pragma unroll
    for (int s = 1; s < KSLOTS; ++s) m = fmaxf(m, sc[s]);
    float ex[KSLOTS], sum = 0.f;
#pragma unroll
    for (int s = 0; s < KSLOTS; ++s) {
      ex[s] = expf(sc[s] - m);
      sum += ex[s];
    }
    const float inv = 1.f / sum;
    float ctx = 0.f;
#pragma unroll
    for (int s = 0; s < KSLOTS; ++s) ctx += (ex[s] * inv) * hw[s];

    // out = ctx@Wo + bo  (Wo from LDS)
    float o = sm.P[384 + lane];
#pragma unroll 8
    for (int i = 0; i < 64; ++i)
      o += __shfl(ctx, i, 64) * s_wo[i * 64 + lane];

    if (BF) ((__hip_bfloat16*)out)[b * 64 + lane] = __float2bfloat16(o);
    else    ((float*)out)[b * 64 + lane] = o;
  }
}

__global__ __launch_bounds__(256, 1) void k_fused(
    const int* __restrict__ seq, const void* __restrict__ embed,
    const void* __restrict__ W1, const void* __restrict__ b1,
    const void* __restrict__ W2, const void* __restrict__ b2,
    const void* __restrict__ gamma, const void* __restrict__ beta,
    const void* __restrict__ Wq, const void* __restrict__ bq,
    const void* __restrict__ Wo, const void* __restrict__ bo,
    void* __restrict__ out) {
  __shared__ Smem sm;  // kernel-scope: shared by both template instantiations
  if (probe_bf16(embed))
    fused_body<true>(seq, embed, W1, b1, W2, b2, gamma, beta, Wq, bq, Wo, bo,
                     out, sm);
  else
    fused_body<false>(seq, embed, W1, b1, W2, b2, gamma, beta, Wq, bq, Wo, bo,
                      out, sm);
}

extern "C" void kernel_launch(void* const* d_in, const int* in_sizes, int n_in,
                              void* d_out, int out_size, void* d_ws, size_t ws_size,
                              hipStream_t stream) {
  const int* seq    = (const int*)d_in[0];
  const void* embed = d_in[1];
  const void* W1    = d_in[2];
  const void* b1    = d_in[3];
  const void* W2    = d_in[4];
  const void* b2    = d_in[5];
  const void* gamma = d_in[6];
  const void* beta  = d_in[7];
  const void* Wq    = d_in[8];
  const void* bq    = d_in[9];
  const void* Wo    = d_in[10];
  const void* bo    = d_in[11];

  k_fused<<<256, 256, 0, stream>>>(seq, embed, W1, b1, W2, b2, gamma, beta,
                                   Wq, bq, Wo, bo, d_out);
}

// Round 9
// 13.930 us; speedup vs baseline: 2.2186x; 2.2186x over previous
//
#include <hip/hip_runtime.h>
#include <hip/hip_bf16.h>

// SlotModel: B=2048, L=512, H=64, VOCAB=64, k=6 slots.
// h[b,l] depends only on token id -> 64-entry tables + per-batch top-6 scan.
// Measured structure decision (rounds 3..8): 2 plain dispatches with a
// NON-redundant producer beat every fused variant (atomic spin 155us,
// grid.sync 55us, per-block redundant producer 25-50us: LDS-broadcast bound).
// This round: round-3 verified structure + DPP wave reductions in the
// consumer (VALU pipe instead of ds_swizzle/ds_bpermute LDS-pipe ops).

#define LSEQ 512
#define BODY 509       // L-3 positions eligible for slots
#define KSLOTS 6
#define INF_KEY 0x7FFFFFFF

// ---- verified swizzle reduction (used only in K1, 64 small blocks) ----
__device__ __forceinline__ float wsum(float x) {
#pragma unroll
  for (int off = 32; off >= 1; off >>= 1) x += __shfl_xor(x, off, 64);
  return x;
}

// ---- DPP full-wave reductions (rocPRIM wave64 pattern) ----
// row_shr:1,2,4,8 builds per-row-16 prefix; row_bcast:15 then row_bcast:31
// chains rows; lane 63 holds the full-wave result; readlane broadcasts.
// update_dpp(old, src, ctrl, row_mask, bank_mask, bound_ctrl=false):
// lanes with no valid source take `old` (= the reduction identity).
__device__ __forceinline__ int dpp_wave_min_i32(int x) {
  int t;
  t = __builtin_amdgcn_update_dpp(INF_KEY, x, 0x111, 0xf, 0xf, false); x = min(x, t);
  t = __builtin_amdgcn_update_dpp(INF_KEY, x, 0x112, 0xf, 0xf, false); x = min(x, t);
  t = __builtin_amdgcn_update_dpp(INF_KEY, x, 0x114, 0xf, 0xf, false); x = min(x, t);
  t = __builtin_amdgcn_update_dpp(INF_KEY, x, 0x118, 0xf, 0xf, false); x = min(x, t);
  t = __builtin_amdgcn_update_dpp(INF_KEY, x, 0x142, 0xf, 0xf, false); x = min(x, t);
  t = __builtin_amdgcn_update_dpp(INF_KEY, x, 0x143, 0xf, 0xf, false); x = min(x, t);
  return __builtin_amdgcn_readlane(x, 63);
}
__device__ __forceinline__ float dpp_wave_sum_f32(float x) {
  int t;
  t = __builtin_amdgcn_update_dpp(0, __float_as_int(x), 0x111, 0xf, 0xf, false); x += __int_as_float(t);
  t = __builtin_amdgcn_update_dpp(0, __float_as_int(x), 0x112, 0xf, 0xf, false); x += __int_as_float(t);
  t = __builtin_amdgcn_update_dpp(0, __float_as_int(x), 0x114, 0xf, 0xf, false); x += __int_as_float(t);
  t = __builtin_amdgcn_update_dpp(0, __float_as_int(x), 0x118, 0xf, 0xf, false); x += __int_as_float(t);
  t = __builtin_amdgcn_update_dpp(0, __float_as_int(x), 0x142, 0xf, 0xf, false); x += __int_as_float(t);
  t = __builtin_amdgcn_update_dpp(0, __float_as_int(x), 0x143, 0xf, 0xf, false); x += __int_as_float(t);
  return __int_as_float(__builtin_amdgcn_readlane(__float_as_int(x), 63));
}
__device__ __forceinline__ float readlane_f(float x, int u) {
  return __int_as_float(__builtin_amdgcn_readlane(__float_as_int(x), u));
}

// Dtype probe (verified rounds 2-8): first 256 ushorts of embed. True bf16
// embed ~N(0,0.02^2) -> exponent < 127; if f32, low-mantissa halves have
// ~random exponents -> detection certain. Wave-uniform.
__device__ __forceinline__ bool probe_bf16(const void* embed) {
  const ushort* e = (const ushort*)embed;
  const int lane = threadIdx.x & 63;
  bool bad = false;
#pragma unroll
  for (int i = 0; i < 4; ++i) {
    const int exp = (e[lane * 4 + i] >> 7) & 0xFF;
    if (exp >= 127) bad = true;
  }
  return !__any(bad);
}

template <bool BF>
__device__ __forceinline__ float ldel(const void* p, int i) {
  if (BF) return __bfloat162float(((const __hip_bfloat16*)p)[i]);
  return ((const float*)p)[i];
}
template <bool BF>
__device__ __forceinline__ float2 ldpair(const void* p, int i) {
  if (BF) {
    const uint u = *(const uint*)((const ushort*)p + i);
    return make_float2(__uint_as_float(u << 16),
                       __uint_as_float(u & 0xFFFF0000u));
  }
  return *(const float2*)((const float*)p + i);
}

// ---- K1 (verified round 3): 64 blocks, one token each. Produces h row,
// q row (=h@Wq+bq), out row (=h@Wo+bo folded), norm. ----
template <bool BF>
__device__ __forceinline__ void k1_body(
    const void* embed, const void* W1, const void* b1, const void* W2,
    const void* b2, const void* gamma, const void* beta, const void* Wq,
    const void* bq, const void* Wo, const void* bo, float* h_table,
    float* norm_table, float* q_table, float* out_table) {
  const int v = blockIdx.x, t = threadIdx.x;
  __shared__ float e_s[64];
  __shared__ float h1_s[128];
  __shared__ float h_s[64];
  e_s[t] = ldel<BF>(embed, v * 64 + t);
  __syncthreads();
  float a0 = ldel<BF>(b1, 2 * t);
  float a1 = ldel<BF>(b1, 2 * t + 1);
#pragma unroll
  for (int k = 0; k < 64; ++k) {
    const float ek = e_s[k];
    const float2 w = ldpair<BF>(W1, k * 128 + 2 * t);
    a0 += ek * w.x;
    a1 += ek * w.y;
  }
  h1_s[2 * t] = fmaxf(a0, 0.f);
  h1_s[2 * t + 1] = fmaxf(a1, 0.f);
  __syncthreads();
  float f = ldel<BF>(b2, t);
#pragma unroll
  for (int j = 0; j < 128; ++j) f += h1_s[j] * ldel<BF>(W2, j * 64 + t);
  const float x = e_s[t] + f;
  const float mu = wsum(x) * (1.f / 64.f);
  const float d = x - mu;
  const float var = wsum(d * d) * (1.f / 64.f);
  const float h = d / sqrtf(var + 1e-5f) * ldel<BF>(gamma, t) + ldel<BF>(beta, t);
  h_table[v * 64 + t] = h;
  h_s[t] = h;
  const float n2 = wsum(h * h);
  if (t == 0) norm_table[v] = sqrtf(n2);
  __syncthreads();
  float q = ldel<BF>(bq, t);
  float o = ldel<BF>(bo, t);   // bo folded: sum(attn)==1
#pragma unroll
  for (int i = 0; i < 64; ++i) {
    const float hi = h_s[i];
    q += hi * ldel<BF>(Wq, i * 64 + t);
    o += hi * ldel<BF>(Wo, i * 64 + t);
  }
  q_table[v * 64 + t] = q;
  out_table[v * 64 + t] = o;
}

__global__ __launch_bounds__(64) void k_tables(
    const void* __restrict__ embed, const void* __restrict__ W1,
    const void* __restrict__ b1, const void* __restrict__ W2,
    const void* __restrict__ b2, const void* __restrict__ gamma,
    const void* __restrict__ beta, const void* __restrict__ Wq,
    const void* __restrict__ bq, const void* __restrict__ Wo,
    const void* __restrict__ bo, float* __restrict__ h_table,
    float* __restrict__ norm_table, float* __restrict__ q_table,
    float* __restrict__ out_table) {
  if (probe_bf16(embed))
    k1_body<true>(embed, W1, b1, W2, b2, gamma, beta, Wq, bq, Wo, bo, h_table,
                  norm_table, q_table, out_table);
  else
    k1_body<false>(embed, W1, b1, W2, b2, gamma, beta, Wq, bq, Wo, bo, h_table,
                   norm_table, q_table, out_table);
}

// ---- K2: 512 blocks x 256, one batch row per wave. Rank-key top-6
// (== jax.lax.top_k desc-stable), DPP reductions, softmax, weighted sum. ----
__global__ __launch_bounds__(256) void k_attn(
    const int* __restrict__ seq, const float* __restrict__ h_table,
    const float* __restrict__ q_table, const float* __restrict__ out_table,
    const float* __restrict__ norm_table, const void* __restrict__ embed,
    void* __restrict__ out) {
  const bool bf = probe_bf16(embed);  // wave-uniform; store dtype only
  const int tid = threadIdx.x;
  const int wave = tid >> 6, lane = tid & 63;
  const int b = blockIdx.x * 4 + wave;
  const int* srow = seq + b * LSEQ;
  const int4 s0 = *(const int4*)(srow + 8 * lane);
  const int4 s1 = *(const int4*)(srow + 8 * lane + 4);

  // rank of token `lane`: count of strictly-greater norms (ties share rank
  // -> stable-by-position tie-break). readlane: constant index, VALU-only.
  const float nv = norm_table[lane];
  int rk = 0;
#pragma unroll
  for (int u = 0; u < 64; ++u) {
    const float nu = readlane_f(nv, u);
    rk += (nu > nv) ? 1 : 0;
  }

  const int vals[8] = {s0.x, s0.y, s0.z, s0.w, s1.x, s1.y, s1.z, s1.w};
  int keys[8];
#pragma unroll
  for (int i = 0; i < 8; ++i) {
    const int p = 8 * lane + i;
    const int r = __shfl(rk, vals[i], 64);  // dynamic gather: ds_bpermute
    keys[i] = (p < BODY) ? ((r << 15) | (p << 6) | vals[i]) : INF_KEY;
  }
  const int v_last = __builtin_amdgcn_readlane(vals[7], 63);  // srow[511]

  int winner[KSLOTS];
#pragma unroll
  for (int s = 0; s < KSLOTS; ++s) {
    int lmin = keys[0];
#pragma unroll
    for (int i = 1; i < 8; ++i) lmin = min(lmin, keys[i]);
    const int gmin = dpp_wave_min_i32(lmin);
    winner[s] = gmin;
    if (lmin == gmin) {  // keys unique (pos field) -> exactly one match
#pragma unroll
      for (int i = 0; i < 8; ++i)
        if (keys[i] == gmin) keys[i] = INF_KEY;
    }
  }

  const float qv = q_table[v_last * 64 + lane];
  float sc[KSLOTS];
#pragma unroll
  for (int s = 0; s < KSLOTS; ++s)
    sc[s] = dpp_wave_sum_f32(qv * h_table[(winner[s] & 63) * 64 + lane]) *
            0.125f;  // /sqrt(64)
  float m = sc[0];
#pragma unroll
  for (int s = 1; s < KSLOTS; ++s) m = fmaxf(m, sc[s]);
  float ex[KSLOTS], sum = 0.f;
#pragma unroll
  for (int s = 0; s < KSLOTS; ++s) {
    ex[s] = expf(sc[s] - m);
    sum += ex[s];
  }
  const float inv = 1.f / sum;
  float acc = 0.f;  // bo already folded into out_table by K1
#pragma unroll
  for (int s = 0; s < KSLOTS; ++s)
    acc += (ex[s] * inv) * out_table[(winner[s] & 63) * 64 + lane];

  if (bf) ((__hip_bfloat16*)out)[b * 64 + lane] = __float2bfloat16(acc);
  else    ((float*)out)[b * 64 + lane] = acc;
}

extern "C" void kernel_launch(void* const* d_in, const int* in_sizes, int n_in,
                              void* d_out, int out_size, void* d_ws, size_t ws_size,
                              hipStream_t stream) {
  const int* seq    = (const int*)d_in[0];
  const void* embed = d_in[1];
  const void* W1    = d_in[2];
  const void* b1    = d_in[3];
  const void* W2    = d_in[4];
  const void* b2    = d_in[5];
  const void* gamma = d_in[6];
  const void* beta  = d_in[7];
  const void* Wq    = d_in[8];
  const void* bq    = d_in[9];
  const void* Wo    = d_in[10];
  const void* bo    = d_in[11];

  float* ws         = (float*)d_ws;
  float* h_table    = ws;          // 4096 f32
  float* norm_table = ws + 4096;   // 64 f32
  float* q_table    = ws + 4224;   // 4096 f32
  float* out_table  = ws + 8320;   // 4096 f32

  k_tables<<<64, 64, 0, stream>>>(embed, W1, b1, W2, b2, gamma, beta, Wq, bq,
                                  Wo, bo, h_table, norm_table, q_table,
                                  out_table);
  k_attn<<<512, 256, 0, stream>>>(seq, h_table, q_table, out_table, norm_table,
                                  embed, d_out);
}